// Round 1
// baseline (2290.406 us; speedup 1.0000x reference)
//
#include <hip/hip_runtime.h>
#include <hip/hip_bf16.h>
#include <math.h>

#define HIDDEN 2048
#define NHEADS 16
#define HEADD  128
#define BB     2
#define LL     2048
#define MM     (BB*LL)   // 4096 rows total

// ---------------------------------------------------------------------------
// Generic fp32 GEMM: C[M,N] = A[M,K] @ W[K,N].  BM=BN=128, BK=16, 256 thr,
// 8x8 micro-tile. A staged transposed in LDS (pad 132) for float4 reads.
// ---------------------------------------------------------------------------
__device__ __forceinline__ void gemm_body(const float* __restrict__ A,
                                          const float* __restrict__ W,
                                          float* __restrict__ C,
                                          int N, int K, int bm, int bn) {
  __shared__ __align__(16) float As[16*132];
  __shared__ __align__(16) float Bs[16*132];
  const int t  = threadIdx.x;
  const int tx = t & 15, ty = t >> 4;

  float acc[8][8] = {};

  for (int k0 = 0; k0 < K; k0 += 16) {
    // A tile: 128 rows x 16 k. float4 loads (2/thread), transposed store.
#pragma unroll
    for (int i = 0; i < 2; i++) {
      int idx4 = t + i*256;           // 0..511
      int r  = idx4 >> 2;             // 0..127
      int kq = idx4 & 3;              // k quad
      const float4 av = *(const float4*)(A + (size_t)(bm + r)*K + k0 + kq*4);
      As[(kq*4+0)*132 + r] = av.x;
      As[(kq*4+1)*132 + r] = av.y;
      As[(kq*4+2)*132 + r] = av.z;
      As[(kq*4+3)*132 + r] = av.w;
    }
    // B tile: 16 k x 128 n, natural layout, float4.
#pragma unroll
    for (int i = 0; i < 2; i++) {
      int idx4 = t + i*256;
      int kk = idx4 >> 5;             // 0..15
      int cq = idx4 & 31;             // 0..31
      *(float4*)(Bs + kk*132 + cq*4) =
          *(const float4*)(W + (size_t)(k0 + kk)*N + bn + cq*4);
    }
    __syncthreads();
#pragma unroll
    for (int kk = 0; kk < 16; kk++) {
      float a[8], b[8];
      *(float4*)&a[0] = *(const float4*)(As + kk*132 + ty*8);
      *(float4*)&a[4] = *(const float4*)(As + kk*132 + ty*8 + 4);
      *(float4*)&b[0] = *(const float4*)(Bs + kk*132 + tx*8);
      *(float4*)&b[4] = *(const float4*)(Bs + kk*132 + tx*8 + 4);
#pragma unroll
      for (int i = 0; i < 8; i++)
#pragma unroll
        for (int j = 0; j < 8; j++)
          acc[i][j] += a[i]*b[j];
    }
    __syncthreads();
  }

#pragma unroll
  for (int i = 0; i < 8; i++) {
    float* dst = C + (size_t)(bm + ty*8 + i)*N + bn + tx*8;
    *(float4*)dst     = make_float4(acc[i][0], acc[i][1], acc[i][2], acc[i][3]);
    *(float4*)(dst+4) = make_float4(acc[i][4], acc[i][5], acc[i][6], acc[i][7]);
  }
}

__global__ __launch_bounds__(256) void gemm_f32(const float* __restrict__ A,
                                                const float* __restrict__ W,
                                                float* __restrict__ C,
                                                int N, int K) {
  gemm_body(A, W, C, N, K, blockIdx.y*128, blockIdx.x*128);
}

// Fused QKV projection: grid.x = 18 n-tiles (16 for Wq, 1 Wk, 1 Wv).
__global__ __launch_bounds__(256) void gemm_qkv(const float* __restrict__ A,
                                                const float* __restrict__ Wq,
                                                const float* __restrict__ Wk,
                                                const float* __restrict__ Wv,
                                                float* __restrict__ qo,
                                                float* __restrict__ ko,
                                                float* __restrict__ vo) {
  const int nt = blockIdx.x;
  const float* W; float* Cc; int N; int bn;
  if (nt < 16)      { W = Wq; Cc = qo; N = 2048; bn = nt*128; }
  else if (nt == 16){ W = Wk; Cc = ko; N = 128;  bn = 0; }
  else              { W = Wv; Cc = vo; N = 128;  bn = 0; }
  gemm_body(A, W, Cc, N, HIDDEN, blockIdx.y*128, bn);
}

// ---------------------------------------------------------------------------
// RoPE, faithful to the reference:
//   out[d]    = cos(p*invf[d/2])    * x[d]    - sin(p*invf[d/2])    * x[d+64]
//   out[d+64] = cos(p*invf[32+d/2]) * x[d+64] + sin(p*invf[32+d/2]) * x[d]
//   invf[i] = 1 / 10000^(2i/128)
// Applied to all 16 q heads and the single k head (head id 16).
// ---------------------------------------------------------------------------
__global__ __launch_bounds__(256) void rope_kernel(float* __restrict__ q,
                                                   float* __restrict__ kk,
                                                   const int* __restrict__ pos) {
  int idx  = blockIdx.x*256 + threadIdx.x;   // over MM*17*64
  int d    = idx & 63;
  int hr   = idx >> 6;
  int head = hr % 17;
  int row  = hr / 17;
  if (row >= MM) return;

  float p = (float)pos[row & (LL-1)];        // row % L
  float* base = (head < 16) ? (q + (size_t)row*HIDDEN + head*HEADD)
                            : (kk + (size_t)row*HEADD);
  float x0 = base[d], x1 = base[d+64];

  float e0 = (float)(d & ~1)          * (1.0f/128.0f);
  float e1 = (float)((d & ~1) + 64)   * (1.0f/128.0f);
  float if0 = 1.0f / powf(10000.0f, e0);
  float if1 = 1.0f / powf(10000.0f, e1);
  float s0, c0, s1, c1;
  sincosf(p * if0, &s0, &c0);
  sincosf(p * if1, &s1, &c1);
  base[d]    = c0*x0 - s0*x1;
  base[d+64] = c1*x1 + s1*x0;
}

// ---------------------------------------------------------------------------
// Flash attention fp32 (non-causal, MQA). One block = one (b,h) x 64 q-rows.
// 256 threads. BQ=64, KB=64 keys per stage.
// LDS: QsT[128][64] (swizzled) + union(KsT[128][64], PsT[64][64]) = 64 KiB.
// S GEMM 4x4 micro; PV 4x8 micro with V streamed from global (L2-resident).
// ---------------------------------------------------------------------------
__device__ __forceinline__ int swz(int row, int col) {
  // quad-granular XOR swizzle within a 64-float LDS row
  return (((col >> 2) ^ (row & 15)) << 2) | (col & 3);
}

__global__ __launch_bounds__(256) void attn_kernel(const float* __restrict__ q,
                                                   const float* __restrict__ k,
                                                   const float* __restrict__ v,
                                                   float* __restrict__ ctx) {
  __shared__ __align__(16) float smem[16384];     // 64 KiB
  float* QsT = smem;            // [128][64]  QsT[dd][r]
  float* KsT = smem + 8192;     // [128][64]  KsT[dd][kc]   (dead after S GEMM)
  float* PsT = smem + 8192;     // [64][64]   PsT[kc][r]    (aliases KsT)

  const int t  = threadIdx.x;
  const int tx = t & 15, ty = t >> 4;
  const int bh = blockIdx.y;
  const int b  = bh >> 4, h = bh & 15;
  const int q0 = blockIdx.x * 64;
  const float scale = 0.08838834764831845f;       // 1/sqrt(128)

  const float* kbase = k + (size_t)b*LL*HEADD;
  const float* vbase = v + (size_t)b*LL*HEADD;

  // stage Q transposed+swizzled, pre-scaled
#pragma unroll
  for (int i = 0; i < 32; i++) {
    int idx = t + (i<<8);
    int r = idx >> 7, dd = idx & 127;
    QsT[dd*64 + swz(dd, r)] =
        q[(size_t)(b*LL + q0 + r)*HIDDEN + h*HEADD + dd] * scale;
  }

  float o[4][8] = {};
  float m_i[4], l_i[4];
#pragma unroll
  for (int i = 0; i < 4; i++) { m_i[i] = -INFINITY; l_i[i] = 0.f; }

  for (int kb = 0; kb < LL; kb += 64) {
    __syncthreads();            // prior PV done with PsT (aliases KsT); Q ready
    // stage K transposed+swizzled
#pragma unroll
    for (int i = 0; i < 32; i++) {
      int idx = t + (i<<8);
      int kc = idx >> 7, dd = idx & 127;
      KsT[dd*64 + swz(dd, kc)] = kbase[(size_t)(kb + kc)*HEADD + dd];
    }
    __syncthreads();

    // S = (scale*Q) K^T : rows ty*4+i, keys tx*4+j
    float s[4][4] = {};
#pragma unroll 8
    for (int dd = 0; dd < 128; dd++) {
      const float4 av = *(const float4*)(QsT + dd*64 + (((ty ^ (dd & 15))) << 2));
      const float4 bv = *(const float4*)(KsT + dd*64 + (((tx ^ (dd & 15))) << 2));
      const float a[4] = {av.x, av.y, av.z, av.w};
      const float bq[4] = {bv.x, bv.y, bv.z, bv.w};
#pragma unroll
      for (int i = 0; i < 4; i++)
#pragma unroll
        for (int j = 0; j < 4; j++)
          s[i][j] += a[i]*bq[j];
    }
    __syncthreads();            // all waves done reading KsT -> PsT write safe

    // online softmax per row (replicated across the 16 tx threads of a row)
#pragma unroll
    for (int i = 0; i < 4; i++) {
      float rmax = fmaxf(fmaxf(s[i][0], s[i][1]), fmaxf(s[i][2], s[i][3]));
#pragma unroll
      for (int mm = 1; mm < 16; mm <<= 1) rmax = fmaxf(rmax, __shfl_xor(rmax, mm, 64));
      float mnew = fmaxf(m_i[i], rmax);
      float corr = expf(m_i[i] - mnew);
      l_i[i] *= corr;
#pragma unroll
      for (int j2 = 0; j2 < 8; j2++) o[i][j2] *= corr;
      float p[4], rs = 0.f;
#pragma unroll
      for (int j = 0; j < 4; j++) { p[j] = expf(s[i][j] - mnew); rs += p[j]; }
#pragma unroll
      for (int mm = 1; mm < 16; mm <<= 1) rs += __shfl_xor(rs, mm, 64);
      l_i[i] += rs;
      m_i[i] = mnew;
#pragma unroll
      for (int j = 0; j < 4; j++) {
        int kc = tx*4 + j;
        PsT[kc*64 + swz(kc, ty*4 + i)] = p[j];
      }
    }
    __syncthreads();            // conservative: PsT visible before PV reads

    // O += P V : rows ty*4+i, cols tx*8+j2. V streamed from global (L2).
#pragma unroll 4
    for (int kc = 0; kc < 64; kc++) {
      const float4 pav = *(const float4*)(PsT + kc*64 + (((ty ^ (kc & 15))) << 2));
      const float pa[4] = {pav.x, pav.y, pav.z, pav.w};
      const float* vrow = vbase + (size_t)(kb + kc)*HEADD + tx*8;
      const float4 v0 = *(const float4*)vrow;
      const float4 v1 = *(const float4*)(vrow + 4);
      const float vv[8] = {v0.x, v0.y, v0.z, v0.w, v1.x, v1.y, v1.z, v1.w};
#pragma unroll
      for (int i = 0; i < 4; i++)
#pragma unroll
        for (int j2 = 0; j2 < 8; j2++)
          o[i][j2] += pa[i]*vv[j2];
    }
  }

  // epilogue: normalize + write ctx[b, q0+r, h*128 + dc]
#pragma unroll
  for (int i = 0; i < 4; i++) {
    float inv = 1.0f / l_i[i];
    float* dst = ctx + (size_t)(b*LL + q0 + ty*4 + i)*HIDDEN + h*HEADD + tx*8;
    *(float4*)dst     = make_float4(o[i][0]*inv, o[i][1]*inv, o[i][2]*inv, o[i][3]*inv);
    *(float4*)(dst+4) = make_float4(o[i][4]*inv, o[i][5]*inv, o[i][6]*inv, o[i][7]*inv);
  }
}

// ---------------------------------------------------------------------------
extern "C" void kernel_launch(void* const* d_in, const int* in_sizes, int n_in,
                              void* d_out, int out_size, void* d_ws, size_t ws_size,
                              hipStream_t stream) {
  const float* hs  = (const float*)d_in[0];
  const int*   pos = (const int*)d_in[1];
  const float* Wq  = (const float*)d_in[2];
  const float* Wk  = (const float*)d_in[3];
  const float* Wv  = (const float*)d_in[4];
  const float* Wo  = (const float*)d_in[5];
  float* out = (float*)d_out;

  float* qws = (float*)d_ws;                    // [MM][2048]
  float* kws = qws + (size_t)MM*HIDDEN;         // [MM][128]
  float* vws = kws + (size_t)MM*HEADD;          // [MM][128]
  float* cws = vws + (size_t)MM*HEADD;          // [MM][2048]

  // QKV projections (fused launch: 18 n-tiles x 32 m-tiles)
  gemm_qkv<<<dim3(18, MM/128), 256, 0, stream>>>(hs, Wq, Wk, Wv, qws, kws, vws);
  // RoPE on q (16 heads) and k (1 head)
  rope_kernel<<<(MM*17*64)/256, 256, 0, stream>>>(qws, kws, pos);
  // Flash attention
  attn_kernel<<<dim3(LL/64, BB*NHEADS), 256, 0, stream>>>(qws, kws, vws, cws);
  // Output projection
  gemm_f32<<<dim3(HIDDEN/128, MM/128), 256, 0, stream>>>(cws, Wo, out, HIDDEN, HIDDEN);
}

// Round 3
// 575.635 us; speedup vs baseline: 3.9789x; 3.9789x over previous
//
#include <hip/hip_runtime.h>
#include <hip/hip_bf16.h>
#include <math.h>

#define HIDDEN 2048
#define NHEADS 16
#define HEADD  128
#define BB     2
#define LL     2048
#define MM     (BB*LL)   // 4096 rows

typedef __attribute__((ext_vector_type(8))) short bf16x8;
typedef __attribute__((ext_vector_type(4))) float f32x4;

#define MFMA16(a,b,c) __builtin_amdgcn_mfma_f32_16x16x32_bf16((a),(b),(c),0,0,0)

__device__ __forceinline__ unsigned short f2bf(float x) {
  unsigned u = __float_as_uint(x);
  u = (u + 0x7fffu + ((u >> 16) & 1u)) >> 16;   // RNE
  return (unsigned short)u;
}

__device__ __forceinline__ bf16x8 pack8(float4 a, float4 b) {
  bf16x8 r;
  r[0]=(short)f2bf(a.x); r[1]=(short)f2bf(a.y); r[2]=(short)f2bf(a.z); r[3]=(short)f2bf(a.w);
  r[4]=(short)f2bf(b.x); r[5]=(short)f2bf(b.y); r[6]=(short)f2bf(b.z); r[7]=(short)f2bf(b.w);
  return r;
}

// ---------------------------------------------------------------------------
// GEMM core: C[128 x 128] tile of A[M][2048] x B[N][2048]^T (B row-major-K
// bf16). A is fp32 (cast during staging) or bf16, per template.
// Reg-staged LDS (NO global_load_lds): each thread owns chunk (row=t>>2,
// kq=t&3) and row+64, ds_write_b128 linear (lane*16B). 2 barriers / K-step.
// 4 waves; wave w computes rows w*32..w*32+31 x all 128 cols: acc[2][8].
// ---------------------------------------------------------------------------
template <bool A_IS_F32>
__device__ __forceinline__ void gemm_core_128(
    const void* __restrict__ Aptr, const unsigned short* __restrict__ B,
    int bm, int bn, f32x4 (&acc)[2][8],
    unsigned short* As, unsigned short* Bs) {
  const int t = threadIdx.x, w = t >> 6, l = t & 63;
  const int lo = l & 15, hi = l >> 4;
  const int K = 2048;
  const int r0 = t >> 2, kq = t & 3;   // staging chunk: rows r0, r0+64; k-chunk kq

#pragma unroll 1
  for (int k0 = 0; k0 < K; k0 += 32) {
#pragma unroll
    for (int h = 0; h < 2; h++) {
      const int row = r0 + h*64;
      bf16x8 av;
      if (A_IS_F32) {
        const float* s = (const float*)Aptr + (size_t)(bm + row)*K + k0 + kq*8;
        av = pack8(*(const float4*)s, *(const float4*)(s + 4));
      } else {
        av = *(const bf16x8*)((const unsigned short*)Aptr +
                              (size_t)(bm + row)*K + k0 + kq*8);
      }
      *(bf16x8*)(As + row*32 + kq*8) = av;
      *(bf16x8*)(Bs + row*32 + kq*8) =
          *(const bf16x8*)(B + (size_t)(bn + row)*K + k0 + kq*8);
    }
    __syncthreads();

    bf16x8 af[2], bfr[8];
#pragma unroll
    for (int m = 0; m < 2; m++)
      af[m] = *(const bf16x8*)(As + (w*32 + m*16 + lo)*32 + hi*8);
#pragma unroll
    for (int n = 0; n < 8; n++)
      bfr[n] = *(const bf16x8*)(Bs + (n*16 + lo)*32 + hi*8);
#pragma unroll
    for (int n = 0; n < 8; n++)
#pragma unroll
      for (int m = 0; m < 2; m++)
        acc[m][n] = MFMA16(af[m], bfr[n], acc[m][n]);
    __syncthreads();
  }
}

// ---------------------------------------------------------------------------
// QKV GEMM (A = fp32 hidden_states, cast in staging) + fused RoPE/scale.
// grid.x = 18 n-tiles: 0..15 -> q head tiles, 16 -> k, 17 -> v(->VT).
// ---------------------------------------------------------------------------
__global__ __launch_bounds__(256) void gemm_qkv(
    const float* __restrict__ hs,             // [4096][2048] fp32
    const unsigned short* __restrict__ WT,    // [2304][2048] bf16 (Wq^T|Wk^T|Wv^T)
    const int* __restrict__ pos,
    unsigned short* __restrict__ qb,          // [4096][2048] bf16 (rope+scale)
    unsigned short* __restrict__ kbf,         // [4096][128]  bf16 (rope)
    unsigned short* __restrict__ vtb) {       // [2][128][2048] bf16 (transposed)
  __shared__ unsigned short As[128*32], Bs[128*32];
  const int nt = blockIdx.x;
  const int bm = blockIdx.y * 128;
  f32x4 acc[2][8];
  const f32x4 zero = {0.f, 0.f, 0.f, 0.f};
#pragma unroll
  for (int m = 0; m < 2; m++)
#pragma unroll
    for (int n = 0; n < 8; n++) acc[m][n] = zero;

  gemm_core_128<true>(hs, WT, bm, nt*128, acc, As, Bs);

  const int t = threadIdx.x, w = t >> 6, l = t & 63;
  const int lo = l & 15, hi = l >> 4;

  if (nt < 17) {
    // RoPE: out[d] = c0*x[d]-s0*x[d+64]; out[d+64] = c1*x[d+64]+s1*x[d]
    // invf(d) = 10000^(-(d&~1)/128); invf(d+64) = invf(d)*0.01 exactly.
    const float sc = (nt < 16) ? 0.08838834764831845f : 1.0f;  // fold 1/sqrt(D) into q
    float if0[4];
#pragma unroll
    for (int n = 0; n < 4; n++) {
      int d0 = n*16 + lo;
      if0[n] = __expf(-(float)(d0 & ~1) * 0.07195578415f);     // ln(1e4)/128
    }
#pragma unroll
    for (int m = 0; m < 2; m++)
#pragma unroll
      for (int i = 0; i < 4; i++) {
        int r = bm + w*32 + m*16 + hi*4 + i;
        float p = (float)pos[r & (LL-1)];
#pragma unroll
        for (int n = 0; n < 4; n++) {
          float a0 = p * if0[n], a1 = a0 * 0.01f;
          float s0 = __sinf(a0), c0 = __cosf(a0);
          float s1 = __sinf(a1), c1 = __cosf(a1);
          float x0 = acc[m][n][i], x1 = acc[m][n+4][i];
          float y0 = (c0*x0 - s0*x1) * sc;
          float y1 = (c1*x1 + s1*x0) * sc;
          if (nt < 16) {
            qb[(size_t)r*2048 + nt*128 + n*16 + lo]      = f2bf(y0);
            qb[(size_t)r*2048 + nt*128 + n*16 + lo + 64] = f2bf(y1);
          } else {
            kbf[(size_t)r*128 + n*16 + lo]      = f2bf(y0);
            kbf[(size_t)r*128 + n*16 + lo + 64] = f2bf(y1);
          }
        }
      }
  } else {
    // V tile -> VT[b][d][l] (transposed, bf16): 4 consecutive rows pack to 8B
    const int b = bm >> 11;
#pragma unroll
    for (int m = 0; m < 2; m++)
#pragma unroll
      for (int n = 0; n < 8; n++) {
        int d  = n*16 + lo;
        int r0 = (bm & (LL-1)) + w*32 + m*16 + hi*4;
        ushort4 pk;
        pk.x = f2bf(acc[m][n][0]); pk.y = f2bf(acc[m][n][1]);
        pk.z = f2bf(acc[m][n][2]); pk.w = f2bf(acc[m][n][3]);
        *(ushort4*)(vtb + (size_t)b*HEADD*LL + (size_t)d*LL + r0) = pk;
      }
  }
}

// ---------------------------------------------------------------------------
// Output projection: out[4096][2048] fp32 = ctx(bf16) @ WoT^T
// ---------------------------------------------------------------------------
__global__ __launch_bounds__(256) void gemm_wo(
    const unsigned short* __restrict__ ctx, const unsigned short* __restrict__ WoT,
    float* __restrict__ out) {
  __shared__ unsigned short As[128*32], Bs[128*32];
  const int nt = blockIdx.x, bm = blockIdx.y * 128;
  f32x4 acc[2][8];
  const f32x4 zero = {0.f, 0.f, 0.f, 0.f};
#pragma unroll
  for (int m = 0; m < 2; m++)
#pragma unroll
    for (int n = 0; n < 8; n++) acc[m][n] = zero;

  gemm_core_128<false>(ctx, WoT, bm, nt*128, acc, As, Bs);

  const int t = threadIdx.x, w = t >> 6, l = t & 63;
  const int lo = l & 15, hi = l >> 4;
#pragma unroll
  for (int m = 0; m < 2; m++)
#pragma unroll
    for (int n = 0; n < 8; n++)
#pragma unroll
      for (int i = 0; i < 4; i++)
        out[(size_t)(bm + w*32 + m*16 + hi*4 + i)*2048 + nt*128 + n*16 + lo] =
            acc[m][n][i];
}

// ---------------------------------------------------------------------------
// Flash attention, bf16 MFMA. Block = 256 thr = 4 waves; wave owns 32 q-rows.
// Q in regs; K/V frags direct from global (L2-resident, 1MB/batch each).
// P goes through 4KB/wave XOR-swizzled LDS (wave-private) to re-lay S-frags
// as A-frags. Identical to round-2 version (validated by call-1 pass).
// ---------------------------------------------------------------------------
__global__ __launch_bounds__(256, 2) void attn_mfma(
    const unsigned short* __restrict__ qb,    // [4096][2048] (scaled, roped)
    const unsigned short* __restrict__ kbf,   // [4096][128]
    const unsigned short* __restrict__ vtb,   // [2][128][2048]
    unsigned short* __restrict__ ctx) {       // [4096][2048] bf16
  __shared__ unsigned short P[4][32*64];      // per-wave P tile, swizzled
  const int t = threadIdx.x, w = t >> 6, l = t & 63;
  const int lo = l & 15, hi = l >> 4;
  const int b = blockIdx.y >> 4, h = blockIdx.y & 15;
  const int q0 = blockIdx.x * 128 + w * 32;

  // Q fragments: qf[m][g] covers rows m*16+lo, d in [g*32, g*32+32)
  bf16x8 qf[2][4];
  const unsigned short* qrow = qb + ((size_t)(b*LL + q0))*2048 + h*128;
#pragma unroll
  for (int m = 0; m < 2; m++) {
    const unsigned short* r = qrow + (size_t)(m*16 + lo)*2048 + hi*8;
#pragma unroll
    for (int g = 0; g < 4; g++) qf[m][g] = *(const bf16x8*)(r + g*32);
  }

  const unsigned short* kp = kbf + (size_t)b*LL*HEADD;
  const unsigned short* vp = vtb + (size_t)b*HEADD*LL;

  f32x4 o[2][8];
  float mst[2][4], lst[2][4];
  const f32x4 zero = {0.f, 0.f, 0.f, 0.f};
#pragma unroll
  for (int m = 0; m < 2; m++) {
#pragma unroll
    for (int n = 0; n < 8; n++) o[m][n] = zero;
#pragma unroll
    for (int i = 0; i < 4; i++) { mst[m][i] = -INFINITY; lst[m][i] = 0.f; }
  }

#pragma unroll 1
  for (int kt = 0; kt < LL; kt += 64) {
    // S = Q K^T for 64 keys: s[m][j], cols kt + j*16 + lo
    f32x4 s[2][4];
#pragma unroll
    for (int m = 0; m < 2; m++)
#pragma unroll
      for (int j = 0; j < 4; j++) s[m][j] = zero;
#pragma unroll
    for (int j = 0; j < 4; j++)
#pragma unroll
      for (int g = 0; g < 4; g++) {
        bf16x8 kf = *(const bf16x8*)(kp + (size_t)(kt + j*16 + lo)*128 + g*32 + hi*8);
        s[0][j] = MFMA16(qf[0][g], kf, s[0][j]);
        s[1][j] = MFMA16(qf[1][g], kf, s[1][j]);
      }

    // online softmax (fp32) + write P (bf16) swizzled: chunk ^= row&7
#pragma unroll
    for (int m = 0; m < 2; m++)
#pragma unroll
      for (int i = 0; i < 4; i++) {
        float v0 = s[m][0][i], v1 = s[m][1][i], v2 = s[m][2][i], v3 = s[m][3][i];
        float rm = fmaxf(fmaxf(v0, v1), fmaxf(v2, v3));
#pragma unroll
        for (int mk = 1; mk < 16; mk <<= 1) rm = fmaxf(rm, __shfl_xor(rm, mk, 64));
        float mo = mst[m][i];
        float mn = fmaxf(mo, rm);
        float corr = __expf(mo - mn);
        float p0 = __expf(v0 - mn), p1 = __expf(v1 - mn);
        float p2 = __expf(v2 - mn), p3 = __expf(v3 - mn);
        float ps = p0 + p1 + p2 + p3;
#pragma unroll
        for (int mk = 1; mk < 16; mk <<= 1) ps += __shfl_xor(ps, mk, 64);
        lst[m][i] = lst[m][i]*corr + ps;
        mst[m][i] = mn;
#pragma unroll
        for (int n = 0; n < 8; n++) o[m][n][i] *= corr;
        int row = m*16 + hi*4 + i;
        unsigned short* pr = &P[w][row*64];
        int sx = row & 7;
        pr[(((0 + (lo >> 3)) ^ sx) << 3) | (lo & 7)] = f2bf(p0);
        pr[(((2 + (lo >> 3)) ^ sx) << 3) | (lo & 7)] = f2bf(p1);
        pr[(((4 + (lo >> 3)) ^ sx) << 3) | (lo & 7)] = f2bf(p2);
        pr[(((6 + (lo >> 3)) ^ sx) << 3) | (lo & 7)] = f2bf(p3);
      }
    __syncthreads();

    // P A-frags: pa[m][f] covers rows m*16+lo, kc in [f*32, f*32+32)
    bf16x8 pa[2][2];
#pragma unroll
    for (int m = 0; m < 2; m++) {
      int row = m*16 + lo;
#pragma unroll
      for (int f = 0; f < 2; f++) {
        int ch = (f*4 + hi) ^ (row & 7);
        pa[m][f] = *(const bf16x8*)(&P[w][row*64 + ch*8]);
      }
    }

    // O += P V  (V^T frags contiguous from VT)
#pragma unroll
    for (int f = 0; f < 2; f++)
#pragma unroll
      for (int n = 0; n < 8; n++) {
        bf16x8 vf = *(const bf16x8*)(vp + (size_t)(n*16 + lo)*LL + kt + f*32 + hi*8);
        o[0][n] = MFMA16(pa[0][f], vf, o[0][n]);
        o[1][n] = MFMA16(pa[1][f], vf, o[1][n]);
      }
    __syncthreads();
  }

  // epilogue: normalize, write ctx bf16
#pragma unroll
  for (int m = 0; m < 2; m++) {
    float inv[4];
#pragma unroll
    for (int i = 0; i < 4; i++) inv[i] = 1.0f / lst[m][i];
#pragma unroll
    for (int n = 0; n < 8; n++)
#pragma unroll
      for (int i = 0; i < 4; i++) {
        size_t r = (size_t)(b*LL + q0 + m*16 + hi*4 + i);
        ctx[r*2048 + h*128 + n*16 + lo] = f2bf(o[m][n][i] * inv[i]);
      }
  }
}

// ---------------------------------------------------------------------------
// Transpose-cast all weights: out[n][k] = bf16(in[k][n]).
// Segments: Wq->WTqkv rows 0..2047, Wk->2048.., Wv->2176.., Wo->WoT.
// ---------------------------------------------------------------------------
__global__ __launch_bounds__(256) void tcast_all(
    const float* __restrict__ Wq, const float* __restrict__ Wk,
    const float* __restrict__ Wv, const float* __restrict__ Wo,
    unsigned short* __restrict__ WTqkv, unsigned short* __restrict__ WoT) {
  __shared__ float T[32][33];
  int bid = blockIdx.x;
  const float* src; unsigned short* dst; int N, rowoff, tile;
  if (bid < 4096)      { src = Wq; dst = WTqkv; N = 2048; rowoff = 0;    tile = bid; }
  else if (bid < 4352) { src = Wk; dst = WTqkv; N = 128;  rowoff = 2048; tile = bid - 4096; }
  else if (bid < 4608) { src = Wv; dst = WTqkv; N = 128;  rowoff = 2176; tile = bid - 4352; }
  else                 { src = Wo; dst = WoT;   N = 2048; rowoff = 0;    tile = bid - 4608; }
  int ntiles = N >> 5;
  int tn = tile & (ntiles - 1), tk = tile / ntiles;
  int tx = threadIdx.x, ty = threadIdx.y;
#pragma unroll
  for (int j = 0; j < 4; j++)
    T[ty + j*8][tx] = src[(size_t)(tk*32 + ty + j*8)*N + tn*32 + tx];
  __syncthreads();
#pragma unroll
  for (int j = 0; j < 4; j++)
    dst[(size_t)(rowoff + tn*32 + ty + j*8)*2048 + tk*32 + tx] = f2bf(T[tx][ty + j*8]);
}

// ---------------------------------------------------------------------------
extern "C" void kernel_launch(void* const* d_in, const int* in_sizes, int n_in,
                              void* d_out, int out_size, void* d_ws, size_t ws_size,
                              hipStream_t stream) {
  const float* hs  = (const float*)d_in[0];
  const int*   pos = (const int*)d_in[1];
  const float* Wq  = (const float*)d_in[2];
  const float* Wk  = (const float*)d_in[3];
  const float* Wv  = (const float*)d_in[4];
  const float* Wo  = (const float*)d_in[5];
  float* out = (float*)d_out;

  char* p = (char*)d_ws;
  unsigned short* WTqkv = (unsigned short*)p; p += (size_t)2304*HIDDEN*2;   //  9.4MB
  unsigned short* WoT   = (unsigned short*)p; p += (size_t)HIDDEN*HIDDEN*2; //  8.4MB
  unsigned short* qb    = (unsigned short*)p; p += (size_t)MM*HIDDEN*2;     // 16.8MB
  unsigned short* kbf   = (unsigned short*)p; p += (size_t)MM*HEADD*2;      //  1.0MB
  unsigned short* vtb   = (unsigned short*)p; p += (size_t)BB*HEADD*LL*2;   //  1.0MB
  unsigned short* ctx   = (unsigned short*)p; p += (size_t)MM*HIDDEN*2;     // 16.8MB
  // total ~53.4MB (round-1's 71.3MB footprint passed; 25% margin below it)

  tcast_all<<<8704, dim3(32, 8), 0, stream>>>(Wq, Wk, Wv, Wo, WTqkv, WoT);
  gemm_qkv<<<dim3(18, MM/128), 256, 0, stream>>>(hs, WTqkv, pos, qb, kbf, vtb);
  attn_mfma<<<dim3(LL/128, BB*NHEADS), 256, 0, stream>>>(qb, kbf, vtb, ctx);
  gemm_wo<<<dim3(HIDDEN/128, MM/128), 256, 0, stream>>>(ctx, WoT, out);
}

// Round 4
// 550.640 us; speedup vs baseline: 4.1595x; 1.0454x over previous
//
#include <hip/hip_runtime.h>
#include <hip/hip_bf16.h>
#include <math.h>

#define HIDDEN 2048
#define NHEADS 16
#define HEADD  128
#define BB     2
#define LL     2048
#define MM     (BB*LL)   // 4096 rows

typedef __attribute__((ext_vector_type(8))) short bf16x8;
typedef __attribute__((ext_vector_type(4))) float f32x4;

#define MFMA16(a,b,c) __builtin_amdgcn_mfma_f32_16x16x32_bf16((a),(b),(c),0,0,0)

__device__ __forceinline__ unsigned short f2bf(float x) {
  unsigned u = __float_as_uint(x);
  u = (u + 0x7fffu + ((u >> 16) & 1u)) >> 16;   // RNE
  return (unsigned short)u;
}

__device__ __forceinline__ bf16x8 pack8(float4 a, float4 b) {
  bf16x8 r;
  r[0]=(short)f2bf(a.x); r[1]=(short)f2bf(a.y); r[2]=(short)f2bf(a.z); r[3]=(short)f2bf(a.w);
  r[4]=(short)f2bf(b.x); r[5]=(short)f2bf(b.y); r[6]=(short)f2bf(b.z); r[7]=(short)f2bf(b.w);
  return r;
}

// ---------------------------------------------------------------------------
// GEMM core: C[128 x 128] tile of A[M][2048] x B[N][2048]^T (B row-major-K
// bf16). A is fp32 (cast during staging) or bf16, per template.
// Reg-staged LDS; 2 barriers / K-step. 4 waves; wave w: rows w*32..+31.
// (unchanged from round 3 — validated)
// ---------------------------------------------------------------------------
template <bool A_IS_F32>
__device__ __forceinline__ void gemm_core_128(
    const void* __restrict__ Aptr, const unsigned short* __restrict__ B,
    int bm, int bn, f32x4 (&acc)[2][8],
    unsigned short* As, unsigned short* Bs) {
  const int t = threadIdx.x, w = t >> 6, l = t & 63;
  const int lo = l & 15, hi = l >> 4;
  const int K = 2048;
  const int r0 = t >> 2, kq = t & 3;   // staging chunk: rows r0, r0+64; k-chunk kq

#pragma unroll 1
  for (int k0 = 0; k0 < K; k0 += 32) {
#pragma unroll
    for (int h = 0; h < 2; h++) {
      const int row = r0 + h*64;
      bf16x8 av;
      if (A_IS_F32) {
        const float* s = (const float*)Aptr + (size_t)(bm + row)*K + k0 + kq*8;
        av = pack8(*(const float4*)s, *(const float4*)(s + 4));
      } else {
        av = *(const bf16x8*)((const unsigned short*)Aptr +
                              (size_t)(bm + row)*K + k0 + kq*8);
      }
      *(bf16x8*)(As + row*32 + kq*8) = av;
      *(bf16x8*)(Bs + row*32 + kq*8) =
          *(const bf16x8*)(B + (size_t)(bn + row)*K + k0 + kq*8);
    }
    __syncthreads();

    bf16x8 af[2], bfr[8];
#pragma unroll
    for (int m = 0; m < 2; m++)
      af[m] = *(const bf16x8*)(As + (w*32 + m*16 + lo)*32 + hi*8);
#pragma unroll
    for (int n = 0; n < 8; n++)
      bfr[n] = *(const bf16x8*)(Bs + (n*16 + lo)*32 + hi*8);
#pragma unroll
    for (int n = 0; n < 8; n++)
#pragma unroll
      for (int m = 0; m < 2; m++)
        acc[m][n] = MFMA16(af[m], bfr[n], acc[m][n]);
    __syncthreads();
  }
}

// ---------------------------------------------------------------------------
// QKV GEMM (A = fp32 hidden_states, cast in staging) + fused RoPE/scale.
// grid.x = 18 n-tiles: 0..15 -> q head tiles, 16 -> k, 17 -> v(->VT).
// ---------------------------------------------------------------------------
__global__ __launch_bounds__(256) void gemm_qkv(
    const float* __restrict__ hs,             // [4096][2048] fp32
    const unsigned short* __restrict__ WT,    // [2304][2048] bf16 (Wq^T|Wk^T|Wv^T)
    const int* __restrict__ pos,
    unsigned short* __restrict__ qb,          // [4096][2048] bf16 (rope+scale)
    unsigned short* __restrict__ kbf,         // [4096][128]  bf16 (rope)
    unsigned short* __restrict__ vtb) {       // [2][128][2048] bf16 (transposed)
  __shared__ unsigned short As[128*32], Bs[128*32];
  const int nt = blockIdx.x;
  const int bm = blockIdx.y * 128;
  f32x4 acc[2][8];
  const f32x4 zero = {0.f, 0.f, 0.f, 0.f};
#pragma unroll
  for (int m = 0; m < 2; m++)
#pragma unroll
    for (int n = 0; n < 8; n++) acc[m][n] = zero;

  gemm_core_128<true>(hs, WT, bm, nt*128, acc, As, Bs);

  const int t = threadIdx.x, w = t >> 6, l = t & 63;
  const int lo = l & 15, hi = l >> 4;

  if (nt < 17) {
    // RoPE: out[d] = c0*x[d]-s0*x[d+64]; out[d+64] = c1*x[d+64]+s1*x[d]
    const float sc = (nt < 16) ? 0.08838834764831845f : 1.0f;  // fold 1/sqrt(D) into q
    float if0[4];
#pragma unroll
    for (int n = 0; n < 4; n++) {
      int d0 = n*16 + lo;
      if0[n] = __expf(-(float)(d0 & ~1) * 0.07195578415f);     // ln(1e4)/128
    }
#pragma unroll
    for (int m = 0; m < 2; m++)
#pragma unroll
      for (int i = 0; i < 4; i++) {
        int r = bm + w*32 + m*16 + hi*4 + i;
        float p = (float)pos[r & (LL-1)];
#pragma unroll
        for (int n = 0; n < 4; n++) {
          float a0 = p * if0[n], a1 = a0 * 0.01f;
          float s0 = __sinf(a0), c0 = __cosf(a0);
          float s1 = __sinf(a1), c1 = __cosf(a1);
          float x0 = acc[m][n][i], x1 = acc[m][n+4][i];
          float y0 = (c0*x0 - s0*x1) * sc;
          float y1 = (c1*x1 + s1*x0) * sc;
          if (nt < 16) {
            qb[(size_t)r*2048 + nt*128 + n*16 + lo]      = f2bf(y0);
            qb[(size_t)r*2048 + nt*128 + n*16 + lo + 64] = f2bf(y1);
          } else {
            kbf[(size_t)r*128 + n*16 + lo]      = f2bf(y0);
            kbf[(size_t)r*128 + n*16 + lo + 64] = f2bf(y1);
          }
        }
      }
  } else {
    // V tile -> VT[b][d][l] (transposed, bf16)
    const int b = bm >> 11;
#pragma unroll
    for (int m = 0; m < 2; m++)
#pragma unroll
      for (int n = 0; n < 8; n++) {
        int d  = n*16 + lo;
        int r0 = (bm & (LL-1)) + w*32 + m*16 + hi*4;
        ushort4 pk;
        pk.x = f2bf(acc[m][n][0]); pk.y = f2bf(acc[m][n][1]);
        pk.z = f2bf(acc[m][n][2]); pk.w = f2bf(acc[m][n][3]);
        *(ushort4*)(vtb + (size_t)b*HEADD*LL + (size_t)d*LL + r0) = pk;
      }
  }
}

// ---------------------------------------------------------------------------
// Output projection: out[4096][2048] fp32 = ctx(bf16) @ WoT^T
// ---------------------------------------------------------------------------
__global__ __launch_bounds__(256) void gemm_wo(
    const unsigned short* __restrict__ ctx, const unsigned short* __restrict__ WoT,
    float* __restrict__ out) {
  __shared__ unsigned short As[128*32], Bs[128*32];
  const int nt = blockIdx.x, bm = blockIdx.y * 128;
  f32x4 acc[2][8];
  const f32x4 zero = {0.f, 0.f, 0.f, 0.f};
#pragma unroll
  for (int m = 0; m < 2; m++)
#pragma unroll
    for (int n = 0; n < 8; n++) acc[m][n] = zero;

  gemm_core_128<false>(ctx, WoT, bm, nt*128, acc, As, Bs);

  const int t = threadIdx.x, w = t >> 6, l = t & 63;
  const int lo = l & 15, hi = l >> 4;
#pragma unroll
  for (int m = 0; m < 2; m++)
#pragma unroll
    for (int n = 0; n < 8; n++)
#pragma unroll
      for (int i = 0; i < 4; i++)
        out[(size_t)(bm + w*32 + m*16 + hi*4 + i)*2048 + nt*128 + n*16 + lo] =
            acc[m][n][i];
}

// ---------------------------------------------------------------------------
// Flash attention, bf16 MFMA. Block = 256 thr = 4 waves; wave owns 32 q-rows.
// Round-4 restructure:
//   * NO __syncthreads(): P[w] is wave-private; only an intra-wave
//     lgkmcnt(0) fence between P ds_writes and P ds_reads is needed.
//     Waves run independently -> each wave's L2 latency hides under
//     other waves' compute.
//   * V-fragment loads hoisted to right after the S-MFMAs: their L2
//     latency hides under the softmax VALU/shfl chain (counted vmcnt
//     keeps K-waits fine-grained; V drains before PV).
// ---------------------------------------------------------------------------
__global__ __launch_bounds__(256, 2) void attn_mfma(
    const unsigned short* __restrict__ qb,    // [4096][2048] (scaled, roped)
    const unsigned short* __restrict__ kbf,   // [4096][128]
    const unsigned short* __restrict__ vtb,   // [2][128][2048]
    unsigned short* __restrict__ ctx) {       // [4096][2048] bf16
  __shared__ unsigned short P[4][32*64];      // per-wave P tile, swizzled
  const int t = threadIdx.x, w = t >> 6, l = t & 63;
  const int lo = l & 15, hi = l >> 4;
  const int b = blockIdx.y >> 4, h = blockIdx.y & 15;
  const int q0 = blockIdx.x * 128 + w * 32;

  // Q fragments: qf[m][g] covers rows m*16+lo, d in [g*32, g*32+32)
  bf16x8 qf[2][4];
  const unsigned short* qrow = qb + ((size_t)(b*LL + q0))*2048 + h*128;
#pragma unroll
  for (int m = 0; m < 2; m++) {
    const unsigned short* r = qrow + (size_t)(m*16 + lo)*2048 + hi*8;
#pragma unroll
    for (int g = 0; g < 4; g++) qf[m][g] = *(const bf16x8*)(r + g*32);
  }

  const unsigned short* kp = kbf + (size_t)b*LL*HEADD;
  const unsigned short* vp = vtb + (size_t)b*HEADD*LL;

  f32x4 o[2][8];
  float mst[2][4], lst[2][4];
  const f32x4 zero = {0.f, 0.f, 0.f, 0.f};
#pragma unroll
  for (int m = 0; m < 2; m++) {
#pragma unroll
    for (int n = 0; n < 8; n++) o[m][n] = zero;
#pragma unroll
    for (int i = 0; i < 4; i++) { mst[m][i] = -INFINITY; lst[m][i] = 0.f; }
  }

#pragma unroll 1
  for (int kt = 0; kt < LL; kt += 64) {
    // S = Q K^T for 64 keys: s[m][j], cols kt + j*16 + lo
    f32x4 s[2][4];
#pragma unroll
    for (int m = 0; m < 2; m++)
#pragma unroll
      for (int j = 0; j < 4; j++) s[m][j] = zero;
#pragma unroll
    for (int j = 0; j < 4; j++)
#pragma unroll
      for (int g = 0; g < 4; g++) {
        bf16x8 kf = *(const bf16x8*)(kp + (size_t)(kt + j*16 + lo)*128 + g*32 + hi*8);
        s[0][j] = MFMA16(qf[0][g], kf, s[0][j]);
        s[1][j] = MFMA16(qf[1][g], kf, s[1][j]);
      }

    // issue all V loads now: latency hides under the softmax chain
    bf16x8 vf[2][8];
#pragma unroll
    for (int f = 0; f < 2; f++)
#pragma unroll
      for (int n = 0; n < 8; n++)
        vf[f][n] = *(const bf16x8*)(vp + (size_t)(n*16 + lo)*LL + kt + f*32 + hi*8);

    // online softmax (fp32) + write P (bf16) swizzled: chunk ^= row&7
#pragma unroll
    for (int m = 0; m < 2; m++)
#pragma unroll
      for (int i = 0; i < 4; i++) {
        float v0 = s[m][0][i], v1 = s[m][1][i], v2 = s[m][2][i], v3 = s[m][3][i];
        float rm = fmaxf(fmaxf(v0, v1), fmaxf(v2, v3));
#pragma unroll
        for (int mk = 1; mk < 16; mk <<= 1) rm = fmaxf(rm, __shfl_xor(rm, mk, 64));
        float mo = mst[m][i];
        float mn = fmaxf(mo, rm);
        float corr = __expf(mo - mn);
        float p0 = __expf(v0 - mn), p1 = __expf(v1 - mn);
        float p2 = __expf(v2 - mn), p3 = __expf(v3 - mn);
        float ps = p0 + p1 + p2 + p3;
#pragma unroll
        for (int mk = 1; mk < 16; mk <<= 1) ps += __shfl_xor(ps, mk, 64);
        lst[m][i] = lst[m][i]*corr + ps;
        mst[m][i] = mn;
#pragma unroll
        for (int n = 0; n < 8; n++) o[m][n][i] *= corr;
        int row = m*16 + hi*4 + i;
        unsigned short* pr = &P[w][row*64];
        int sx = row & 7;
        pr[(((0 + (lo >> 3)) ^ sx) << 3) | (lo & 7)] = f2bf(p0);
        pr[(((2 + (lo >> 3)) ^ sx) << 3) | (lo & 7)] = f2bf(p1);
        pr[(((4 + (lo >> 3)) ^ sx) << 3) | (lo & 7)] = f2bf(p2);
        pr[(((6 + (lo >> 3)) ^ sx) << 3) | (lo & 7)] = f2bf(p3);
      }

    // intra-wave fence: P writes (and shfl swizzles) drained before P reads.
    asm volatile("s_waitcnt lgkmcnt(0)" ::: "memory");
    __builtin_amdgcn_sched_barrier(0);

    // P A-frags: pa[m][f] covers rows m*16+lo, kc in [f*32, f*32+32)
    bf16x8 pa[2][2];
#pragma unroll
    for (int m = 0; m < 2; m++) {
      int row = m*16 + lo;
#pragma unroll
      for (int f = 0; f < 2; f++) {
        int ch = (f*4 + hi) ^ (row & 7);
        pa[m][f] = *(const bf16x8*)(&P[w][row*64 + ch*8]);
      }
    }

    // O += P V  (V already in regs)
#pragma unroll
    for (int f = 0; f < 2; f++)
#pragma unroll
      for (int n = 0; n < 8; n++) {
        o[0][n] = MFMA16(pa[0][f], vf[f][n], o[0][n]);
        o[1][n] = MFMA16(pa[1][f], vf[f][n], o[1][n]);
      }
  }

  // epilogue: normalize, write ctx bf16
#pragma unroll
  for (int m = 0; m < 2; m++) {
    float inv[4];
#pragma unroll
    for (int i = 0; i < 4; i++) inv[i] = 1.0f / lst[m][i];
#pragma unroll
    for (int n = 0; n < 8; n++)
#pragma unroll
      for (int i = 0; i < 4; i++) {
        size_t r = (size_t)(b*LL + q0 + m*16 + hi*4 + i);
        ctx[r*2048 + h*128 + n*16 + lo] = f2bf(o[m][n][i] * inv[i]);
      }
  }
}

// ---------------------------------------------------------------------------
// Transpose-cast all weights: out[n][k] = bf16(in[k][n]).
// ---------------------------------------------------------------------------
__global__ __launch_bounds__(256) void tcast_all(
    const float* __restrict__ Wq, const float* __restrict__ Wk,
    const float* __restrict__ Wv, const float* __restrict__ Wo,
    unsigned short* __restrict__ WTqkv, unsigned short* __restrict__ WoT) {
  __shared__ float T[32][33];
  int bid = blockIdx.x;
  const float* src; unsigned short* dst; int N, rowoff, tile;
  if (bid < 4096)      { src = Wq; dst = WTqkv; N = 2048; rowoff = 0;    tile = bid; }
  else if (bid < 4352) { src = Wk; dst = WTqkv; N = 128;  rowoff = 2048; tile = bid - 4096; }
  else if (bid < 4608) { src = Wv; dst = WTqkv; N = 128;  rowoff = 2176; tile = bid - 4352; }
  else                 { src = Wo; dst = WoT;   N = 2048; rowoff = 0;    tile = bid - 4608; }
  int ntiles = N >> 5;
  int tn = tile & (ntiles - 1), tk = tile / ntiles;
  int tx = threadIdx.x, ty = threadIdx.y;
#pragma unroll
  for (int j = 0; j < 4; j++)
    T[ty + j*8][tx] = src[(size_t)(tk*32 + ty + j*8)*N + tn*32 + tx];
  __syncthreads();
#pragma unroll
  for (int j = 0; j < 4; j++)
    dst[(size_t)(rowoff + tn*32 + ty + j*8)*2048 + tk*32 + tx] = f2bf(T[tx][ty + j*8]);
}

// ---------------------------------------------------------------------------
extern "C" void kernel_launch(void* const* d_in, const int* in_sizes, int n_in,
                              void* d_out, int out_size, void* d_ws, size_t ws_size,
                              hipStream_t stream) {
  const float* hs  = (const float*)d_in[0];
  const int*   pos = (const int*)d_in[1];
  const float* Wq  = (const float*)d_in[2];
  const float* Wk  = (const float*)d_in[3];
  const float* Wv  = (const float*)d_in[4];
  const float* Wo  = (const float*)d_in[5];
  float* out = (float*)d_out;

  char* p = (char*)d_ws;
  unsigned short* WTqkv = (unsigned short*)p; p += (size_t)2304*HIDDEN*2;   //  9.4MB
  unsigned short* WoT   = (unsigned short*)p; p += (size_t)HIDDEN*HIDDEN*2; //  8.4MB
  unsigned short* qb    = (unsigned short*)p; p += (size_t)MM*HIDDEN*2;     // 16.8MB
  unsigned short* kbf   = (unsigned short*)p; p += (size_t)MM*HEADD*2;      //  1.0MB
  unsigned short* vtb   = (unsigned short*)p; p += (size_t)BB*HEADD*LL*2;   //  1.0MB
  unsigned short* ctx   = (unsigned short*)p; p += (size_t)MM*HIDDEN*2;     // 16.8MB
  // total ~53.4MB

  tcast_all<<<8704, dim3(32, 8), 0, stream>>>(Wq, Wk, Wv, Wo, WTqkv, WoT);
  gemm_qkv<<<dim3(18, MM/128), 256, 0, stream>>>(hs, WTqkv, pos, qb, kbf, vtb);
  attn_mfma<<<dim3(LL/128, BB*NHEADS), 256, 0, stream>>>(qb, kbf, vtb, ctx);
  gemm_wo<<<dim3(HIDDEN/128, MM/128), 256, 0, stream>>>(ctx, WoT, out);
}